// Round 1
// baseline (427.043 us; speedup 1.0000x reference)
//
#include <hip/hip_runtime.h>

// GCN 2-layer: x[N,128] -> GCNConv(W1[128,64]) -> relu -> GCNConv(W2[64,32])
// Factored norm: out[d] = dis[d] * sum_{e: dst=d} g[src] + b,  g = (x@W)*dis
// Self-loop handled by initializing accumulator a = g.

#define F_IN 128
#define F_MID 64
#define F_OUT 32

__global__ void k_deg_init(int* __restrict__ deg, int n) {
    int i = blockIdx.x * blockDim.x + threadIdx.x;
    if (i < n) deg[i] = 1;  // self-loop
}

__global__ void k_deg_edges(const int* __restrict__ dst, int E, int* __restrict__ deg) {
    int e = blockIdx.x * blockDim.x + threadIdx.x;
    if (e < E) atomicAdd(&deg[dst[e]], 1);
}

__global__ void k_dis(const int* __restrict__ deg, float* __restrict__ dis, int n) {
    int i = blockIdx.x * blockDim.x + threadIdx.x;
    if (i < n) dis[i] = rsqrtf((float)deg[i]);
}

// g1[r,f] = (x[r,:] @ W1[:,f]) * dis[r];  a1 = g1 (self-loop init)
// block: 256 threads = 4 waves; 16 rows/block; thread computes 4 rows x 1 col
__global__ __launch_bounds__(256) void k_gemm1(
    const float* __restrict__ x, const float* __restrict__ W1,
    const float* __restrict__ dis,
    float* __restrict__ g1, float* __restrict__ a1, int n) {
    __shared__ float Ws[F_IN * F_MID];   // 32 KB
    __shared__ float xs[16 * F_IN];      // 8 KB
    int tid = threadIdx.x;
    for (int i = tid; i < F_IN * F_MID; i += 256) Ws[i] = W1[i];
    int row0 = blockIdx.x * 16;
    for (int i = tid; i < 16 * F_IN; i += 256) {
        int r = row0 + (i >> 7);
        xs[i] = (r < n) ? x[(size_t)r * F_IN + (i & 127)] : 0.0f;
    }
    __syncthreads();
    int f  = tid & 63;
    int rs = tid >> 6;  // wave id 0..3
    float acc[4] = {0.f, 0.f, 0.f, 0.f};
    for (int k = 0; k < F_IN; ++k) {
        float wv = Ws[k * F_MID + f];
#pragma unroll
        for (int j = 0; j < 4; ++j)
            acc[j] += xs[(rs * 4 + j) * F_IN + k] * wv;
    }
#pragma unroll
    for (int j = 0; j < 4; ++j) {
        int r = row0 + rs * 4 + j;
        if (r < n) {
            float v = acc[j] * dis[r];
            g1[(size_t)r * F_MID + f] = v;
            a1[(size_t)r * F_MID + f] = v;
        }
    }
}

// one wave (64 lanes) per edge: a1[dst, f] += g1[src, f]
__global__ void k_scatter1(const int* __restrict__ src, const int* __restrict__ dst,
                           int E, const float* __restrict__ g1, float* __restrict__ a1) {
    long long t = (long long)blockIdx.x * blockDim.x + threadIdx.x;
    int e = (int)(t >> 6);
    int f = (int)(t & 63);
    if (e < E) {
        int s = src[e], d = dst[e];
        atomicAdd(&a1[(size_t)d * F_MID + f], g1[(size_t)s * F_MID + f]);
    }
}

// h[r,f] = relu(a1[r,f]*dis[r] + b1[f]);  g2[r,j] = (h @ W2)[r,j] * dis[r]; a2 = g2
// block: 256 threads; 8 rows/block; thread computes 1 row x 1 col (j = tid&31)
__global__ __launch_bounds__(256) void k_gemm2(
    const float* __restrict__ a1, const float* __restrict__ W2,
    const float* __restrict__ b1, const float* __restrict__ dis,
    float* __restrict__ g2, float* __restrict__ a2, int n) {
    __shared__ float Ws[F_MID * F_OUT];  // 8 KB
    __shared__ float hs[8 * F_MID];      // 2 KB
    int tid = threadIdx.x;
    for (int i = tid; i < F_MID * F_OUT; i += 256) Ws[i] = W2[i];
    int row0 = blockIdx.x * 8;
    for (int i = tid; i < 8 * F_MID; i += 256) {
        int r = row0 + (i >> 6);
        int f = i & 63;
        float v = 0.0f;
        if (r < n) v = fmaxf(a1[(size_t)r * F_MID + f] * dis[r] + b1[f], 0.0f);
        hs[i] = v;
    }
    __syncthreads();
    int j  = tid & 31;
    int rs = tid >> 5;  // 0..7
    int r = row0 + rs;
    float acc = 0.0f;
    for (int k = 0; k < F_MID; ++k)
        acc += hs[rs * F_MID + k] * Ws[k * F_OUT + j];
    if (r < n) {
        float v = acc * dis[r];
        g2[(size_t)r * F_OUT + j] = v;
        a2[(size_t)r * F_OUT + j] = v;
    }
}

// half-wave (32 lanes) per edge: a2[dst, f] += g2[src, f]
__global__ void k_scatter2(const int* __restrict__ src, const int* __restrict__ dst,
                           int E, const float* __restrict__ g2, float* __restrict__ a2) {
    long long t = (long long)blockIdx.x * blockDim.x + threadIdx.x;
    int e = (int)(t >> 5);
    int f = (int)(t & 31);
    if (e < E) {
        int s = src[e], d = dst[e];
        atomicAdd(&a2[(size_t)d * F_OUT + f], g2[(size_t)s * F_OUT + f]);
    }
}

// in-place epilogue on d_out: out = out*dis[i] + b2[j]
__global__ void k_epilogue(float* __restrict__ out, const float* __restrict__ dis,
                           const float* __restrict__ b2, int n) {
    int t = blockIdx.x * blockDim.x + threadIdx.x;
    if (t < n * F_OUT) {
        int i = t >> 5, j = t & 31;
        out[t] = out[t] * dis[i] + b2[j];
    }
}

extern "C" void kernel_launch(void* const* d_in, const int* in_sizes, int n_in,
                              void* d_out, int out_size, void* d_ws, size_t ws_size,
                              hipStream_t stream) {
    const float* x  = (const float*)d_in[0];
    const int*   ei = (const int*)d_in[1];
    const float* W1 = (const float*)d_in[2];
    const float* b1 = (const float*)d_in[3];
    const float* W2 = (const float*)d_in[4];
    const float* b2 = (const float*)d_in[5];

    int n = in_sizes[0] / F_IN;   // 50000
    int E = in_sizes[1] / 2;      // 800000
    const int* src = ei;
    const int* dst = ei + E;

    char* ws = (char*)d_ws;
    size_t off = 0;
    auto alloc = [&](size_t bytes) {
        char* p = ws + off;
        off += (bytes + 255) & ~(size_t)255;
        return p;
    };
    int*   deg = (int*)  alloc((size_t)n * 4);
    float* dis = (float*)alloc((size_t)n * 4);
    float* g1  = (float*)alloc((size_t)n * F_MID * 4);
    float* a1  = (float*)alloc((size_t)n * F_MID * 4);
    float* g2  = (float*)alloc((size_t)n * F_OUT * 4);
    float* a2  = (float*)d_out;   // layer-2 accumulator lives in d_out

    int B = 256;
    k_deg_init<<<(n + B - 1) / B, B, 0, stream>>>(deg, n);
    k_deg_edges<<<(E + B - 1) / B, B, 0, stream>>>(dst, E, deg);
    k_dis<<<(n + B - 1) / B, B, 0, stream>>>(deg, dis, n);

    k_gemm1<<<(n + 15) / 16, 256, 0, stream>>>(x, W1, dis, g1, a1, n);

    long long t1 = (long long)E * 64;
    k_scatter1<<<(unsigned)((t1 + B - 1) / B), B, 0, stream>>>(src, dst, E, g1, a1);

    k_gemm2<<<(n + 7) / 8, 256, 0, stream>>>(a1, W2, b1, dis, g2, a2, n);

    long long t2 = (long long)E * 32;
    k_scatter2<<<(unsigned)((t2 + B - 1) / B), B, 0, stream>>>(src, dst, E, g2, a2);

    k_epilogue<<<((n * F_OUT) + B - 1) / B, B, 0, stream>>>(a2, dis, b2, n);
}

// Round 2
// 307.325 us; speedup vs baseline: 1.3895x; 1.3895x over previous
//
#include <hip/hip_runtime.h>

// GCN 2-layer: x[N,128] -> GCNConv(W1[128,64]) -> relu -> GCNConv(W2[64,32])
// Factored norm: out[d] = dis[d] * (g[d] + sum_{e: dst=d} g[src]) + b,
//   g = (x@W)*dis,  self-loop = the g[d] term.
// R1: scatter-atomics -> CSR build + gather (no fp32 atomics).

#define F_IN 128
#define F_MID 64
#define F_OUT 32
#define SCAN_B 256

__global__ void k_deg_init(int* __restrict__ deg, int n) {
    int i = blockIdx.x * blockDim.x + threadIdx.x;
    if (i < n) deg[i] = 1;  // self-loop
}

__global__ void k_deg_edges(const int* __restrict__ dst, int E, int* __restrict__ deg) {
    int e = blockIdx.x * blockDim.x + threadIdx.x;
    if (e < E) atomicAdd(&deg[dst[e]], 1);
}

__global__ void k_dis(const int* __restrict__ deg, float* __restrict__ dis, int n) {
    int i = blockIdx.x * blockDim.x + threadIdx.x;
    if (i < n) dis[i] = rsqrtf((float)deg[i]);
}

// ---- 3-phase exclusive scan of indeg (= deg-1) -> rowstart, cursor ----
__global__ __launch_bounds__(SCAN_B) void k_scan_partial(
    const int* __restrict__ deg, int n, int* __restrict__ bsum) {
    __shared__ int s[SCAN_B];
    int i = blockIdx.x * SCAN_B + threadIdx.x;
    s[threadIdx.x] = (i < n) ? (deg[i] - 1) : 0;
    __syncthreads();
    for (int o = SCAN_B / 2; o > 0; o >>= 1) {
        if (threadIdx.x < o) s[threadIdx.x] += s[threadIdx.x + o];
        __syncthreads();
    }
    if (threadIdx.x == 0) bsum[blockIdx.x] = s[0];
}

__global__ __launch_bounds__(SCAN_B) void k_scan_bsums(int* __restrict__ bsum, int nb) {
    __shared__ int s[SCAN_B];
    int t = threadIdx.x;
    int v = (t < nb) ? bsum[t] : 0;
    s[t] = v;
    __syncthreads();
    // Hillis-Steele inclusive
    for (int o = 1; o < SCAN_B; o <<= 1) {
        int add = (t >= o) ? s[t - o] : 0;
        __syncthreads();
        s[t] += add;
        __syncthreads();
    }
    if (t < nb) bsum[t] = s[t] - v;  // exclusive
}

__global__ __launch_bounds__(SCAN_B) void k_scan_final(
    const int* __restrict__ deg, int n, const int* __restrict__ bsum,
    int* __restrict__ rowstart, int* __restrict__ cursor) {
    __shared__ int s[SCAN_B];
    int i = blockIdx.x * SCAN_B + threadIdx.x;
    int t = threadIdx.x;
    int v = (i < n) ? (deg[i] - 1) : 0;
    s[t] = v;
    __syncthreads();
    for (int o = 1; o < SCAN_B; o <<= 1) {
        int add = (t >= o) ? s[t - o] : 0;
        __syncthreads();
        s[t] += add;
        __syncthreads();
    }
    if (i < n) {
        int ex = s[t] - v + bsum[blockIdx.x];
        rowstart[i] = ex;
        cursor[i] = ex;
    }
}

__global__ void k_fill(const int* __restrict__ src, const int* __restrict__ dst,
                       int E, int* __restrict__ cursor, int* __restrict__ col) {
    int e = blockIdx.x * blockDim.x + threadIdx.x;
    if (e < E) {
        int d = dst[e];
        int pos = atomicAdd(&cursor[d], 1);
        col[pos] = src[e];
    }
}

// g1[r,f] = (x[r,:] @ W1[:,f]) * dis[r]
__global__ __launch_bounds__(256) void k_gemm1(
    const float* __restrict__ x, const float* __restrict__ W1,
    const float* __restrict__ dis, float* __restrict__ g1, int n) {
    __shared__ float Ws[F_IN * F_MID];   // 32 KB
    __shared__ float xs[16 * F_IN];      // 8 KB
    int tid = threadIdx.x;
    for (int i = tid; i < F_IN * F_MID; i += 256) Ws[i] = W1[i];
    int row0 = blockIdx.x * 16;
    for (int i = tid; i < 16 * F_IN; i += 256) {
        int r = row0 + (i >> 7);
        xs[i] = (r < n) ? x[(size_t)r * F_IN + (i & 127)] : 0.0f;
    }
    __syncthreads();
    int f  = tid & 63;
    int rs = tid >> 6;
    float acc[4] = {0.f, 0.f, 0.f, 0.f};
    for (int k = 0; k < F_IN; ++k) {
        float wv = Ws[k * F_MID + f];
#pragma unroll
        for (int j = 0; j < 4; ++j)
            acc[j] += xs[(rs * 4 + j) * F_IN + k] * wv;
    }
#pragma unroll
    for (int j = 0; j < 4; ++j) {
        int r = row0 + rs * 4 + j;
        if (r < n) g1[(size_t)r * F_MID + f] = acc[j] * dis[r];
    }
}

// one wave per dst row: h[d,f] = relu(dis[d]*(g1[d,f] + sum_nbrs g1[s,f]) + b1[f])
__global__ __launch_bounds__(256) void k_gather1(
    const int* __restrict__ rowstart, const int* __restrict__ deg,
    const int* __restrict__ col, const float* __restrict__ g1,
    const float* __restrict__ dis, const float* __restrict__ b1,
    float* __restrict__ h, int n) {
    int wave = threadIdx.x >> 6;
    int f    = threadIdx.x & 63;
    int d    = blockIdx.x * 4 + wave;
    if (d >= n) return;
    int base = rowstart[d];
    int cnt  = deg[d] - 1;
    float acc = g1[(size_t)d * F_MID + f];  // self-loop
    for (int i0 = 0; i0 < cnt; i0 += 64) {
        int m = cnt - i0; if (m > 64) m = 64;
        int e = (i0 + f < cnt) ? col[base + i0 + f] : 0;
        for (int j = 0; j < m; ++j) {
            int s = __shfl(e, j);
            acc += g1[(size_t)s * F_MID + f];
        }
    }
    h[(size_t)d * F_MID + f] = fmaxf(acc * dis[d] + b1[f], 0.0f);
}

// g2[r,j] = (h[r,:] @ W2[:,j]) * dis[r]
__global__ __launch_bounds__(256) void k_gemm2(
    const float* __restrict__ h, const float* __restrict__ W2,
    const float* __restrict__ dis, float* __restrict__ g2, int n) {
    __shared__ float Ws[F_MID * F_OUT];  // 8 KB
    __shared__ float hs[8 * F_MID];      // 2 KB
    int tid = threadIdx.x;
    for (int i = tid; i < F_MID * F_OUT; i += 256) Ws[i] = W2[i];
    int row0 = blockIdx.x * 8;
    for (int i = tid; i < 8 * F_MID; i += 256) {
        int r = row0 + (i >> 6);
        hs[i] = (r < n) ? h[(size_t)r * F_MID + (i & 63)] : 0.0f;
    }
    __syncthreads();
    int j  = tid & 31;
    int rs = tid >> 5;
    int r = row0 + rs;
    float acc = 0.0f;
    for (int k = 0; k < F_MID; ++k)
        acc += hs[rs * F_MID + k] * Ws[k * F_OUT + j];
    if (r < n) g2[(size_t)r * F_OUT + j] = acc * dis[r];
}

// half-wave per dst row: out[d,j] = dis[d]*(g2[d,j] + sum_nbrs g2[s,j]) + b2[j]
__global__ __launch_bounds__(256) void k_gather2(
    const int* __restrict__ rowstart, const int* __restrict__ deg,
    const int* __restrict__ col, const float* __restrict__ g2,
    const float* __restrict__ dis, const float* __restrict__ b2,
    float* __restrict__ out, int n) {
    int hw = threadIdx.x >> 5;          // 0..7
    int j  = threadIdx.x & 31;
    int d  = blockIdx.x * 8 + hw;
    if (d >= n) return;
    int base = rowstart[d];
    int cnt  = deg[d] - 1;
    float acc = g2[(size_t)d * F_OUT + j];  // self-loop
    for (int i0 = 0; i0 < cnt; i0 += 32) {
        int m = cnt - i0; if (m > 32) m = 32;
        int e = (i0 + j < cnt) ? col[base + i0 + j] : 0;
        for (int q = 0; q < m; ++q) {
            int s = __shfl(e, q, 32);
            acc += g2[(size_t)s * F_OUT + j];
        }
    }
    out[(size_t)d * F_OUT + j] = acc * dis[d] + b2[j];
}

extern "C" void kernel_launch(void* const* d_in, const int* in_sizes, int n_in,
                              void* d_out, int out_size, void* d_ws, size_t ws_size,
                              hipStream_t stream) {
    const float* x  = (const float*)d_in[0];
    const int*   ei = (const int*)d_in[1];
    const float* W1 = (const float*)d_in[2];
    const float* b1 = (const float*)d_in[3];
    const float* W2 = (const float*)d_in[4];
    const float* b2 = (const float*)d_in[5];

    int n = in_sizes[0] / F_IN;   // 50000
    int E = in_sizes[1] / 2;      // 800000
    const int* src = ei;
    const int* dst = ei + E;

    char* ws = (char*)d_ws;
    size_t off = 0;
    auto alloc = [&](size_t bytes) {
        char* p = ws + off;
        off += (bytes + 255) & ~(size_t)255;
        return p;
    };
    int*   deg      = (int*)  alloc((size_t)n * 4);
    float* dis      = (float*)alloc((size_t)n * 4);
    int*   rowstart = (int*)  alloc((size_t)n * 4);
    int*   cursor   = (int*)  alloc((size_t)n * 4);
    int*   bsum     = (int*)  alloc((size_t)SCAN_B * 4);
    int*   col      = (int*)  alloc((size_t)E * 4);
    float* g1       = (float*)alloc((size_t)n * F_MID * 4);
    float* h        = (float*)alloc((size_t)n * F_MID * 4);
    float* g2       = (float*)alloc((size_t)n * F_OUT * 4);

    int B = 256;
    int nb = (n + SCAN_B - 1) / SCAN_B;  // 196 (< SCAN_B, required by k_scan_bsums)

    k_deg_init<<<(n + B - 1) / B, B, 0, stream>>>(deg, n);
    k_deg_edges<<<(E + B - 1) / B, B, 0, stream>>>(dst, E, deg);
    k_dis<<<(n + B - 1) / B, B, 0, stream>>>(deg, dis, n);

    k_scan_partial<<<nb, SCAN_B, 0, stream>>>(deg, n, bsum);
    k_scan_bsums<<<1, SCAN_B, 0, stream>>>(bsum, nb);
    k_scan_final<<<nb, SCAN_B, 0, stream>>>(deg, n, bsum, rowstart, cursor);

    k_fill<<<(E + B - 1) / B, B, 0, stream>>>(src, dst, E, cursor, col);

    k_gemm1<<<(n + 15) / 16, 256, 0, stream>>>(x, W1, dis, g1, n);
    k_gather1<<<(n + 3) / 4, 256, 0, stream>>>(rowstart, deg, col, g1, dis, b1, h, n);
    k_gemm2<<<(n + 7) / 8, 256, 0, stream>>>(h, W2, dis, g2, n);
    k_gather2<<<(n + 7) / 8, 256, 0, stream>>>(rowstart, deg, col, g2, dis, b2,
                                               (float*)d_out, n);
}